// Round 5
// baseline (354.450 us; speedup 1.0000x reference)
//
#include <hip/hip_runtime.h>

// Problem constants
#define BATCH 2
#define SEQ   2048
#define DIM   1024
#define NHEAD 16
#define HD    64
#define BH    (BATCH * NHEAD)   // 32
#define SCALE 0.125f            // 64^-0.5

typedef __attribute__((ext_vector_type(8))) short short8;
typedef __attribute__((ext_vector_type(4))) float f32x4;

#define MFMA16(a, b, c) __builtin_amdgcn_mfma_f32_16x16x32_bf16(a, b, c, 0, 0, 0)

__device__ __forceinline__ ushort f2bf(float f) {
    union { float f; unsigned u; } v;
    v.f = f;
    unsigned r = (v.u + 0x7FFF + ((v.u >> 16) & 1)) >> 16;   // RNE
    return (ushort)r;
}

// load 8 contiguous elements as 8 bf16 packed in a uint4 (16B)
__device__ __forceinline__ uint4 ld8_bf16(const ushort* p) {
    return *(const uint4*)p;
}
__device__ __forceinline__ uint4 ld8_bf16(const float* p) {
    float4 f0 = *(const float4*)p;
    float4 f1 = *(const float4*)(p + 4);
    union { ushort us[8]; uint4 v; } u;
    u.us[0] = f2bf(f0.x); u.us[1] = f2bf(f0.y);
    u.us[2] = f2bf(f0.z); u.us[3] = f2bf(f0.w);
    u.us[4] = f2bf(f1.x); u.us[5] = f2bf(f1.y);
    u.us[6] = f2bf(f1.z); u.us[7] = f2bf(f1.w);
    return u.v;
}

// ---------------------------------------------------------------------------
// GEMM: C[M,N] = A[M,K] @ W[N,K]^T + bias[N]
// A dtype TA (float for x, ushort/bf16 for wa); W,bias fp32.
// MODE 0: scatter bf16 into qkv workspace [3][B][H][SEQ][HD]  (TOUT=ushort)
// MODE 1: plain row-major fp32 out [M,N]                      (TOUT=float)
// 128x128 tile, BK=32, 4 waves (2x2), each wave 64x64 via 4x4 MFMA 16x16x32.
// ---------------------------------------------------------------------------
template <int MODE, typename TA, typename TOUT>
__global__ __launch_bounds__(256, 2) void gemm_bt(
    const TA* __restrict__ A, const float* __restrict__ W,
    const float* __restrict__ bias, TOUT* __restrict__ out,
    int M, int Nout, int K)
{
    __shared__ __align__(16) ushort As[128 * 32];
    __shared__ __align__(16) ushort Bs[128 * 32];

    const int tid  = threadIdx.x;
    const int wave = tid >> 6, lane = tid & 63;
    const int quad = lane >> 4, l16 = lane & 15;
    const int wm = wave >> 1, wn = wave & 1;
    const int m0 = blockIdx.y * 128, n0 = blockIdx.x * 128;

    // staging: 512 chunks of 8 elements. chunk c -> row c>>2, colblk c&3.
    // thread handles chunks tid and tid+256.
    const int c0 = tid, c1 = tid + 256;
    const TA*    gA0 = A + (size_t)(m0 + (c0 >> 2)) * K + (c0 & 3) * 8;
    const TA*    gA1 = A + (size_t)(m0 + (c1 >> 2)) * K + (c1 & 3) * 8;
    const float* gB0 = W + (size_t)(n0 + (c0 >> 2)) * K + (c0 & 3) * 8;
    const float* gB1 = W + (size_t)(n0 + (c1 >> 2)) * K + (c1 & 3) * 8;

    f32x4 acc[4][4];
#pragma unroll
    for (int i = 0; i < 4; i++)
#pragma unroll
        for (int j = 0; j < 4; j++) acc[i][j] = (f32x4){0.f, 0.f, 0.f, 0.f};

    for (int k0 = 0; k0 < K; k0 += 32) {
        uint4 ra0 = ld8_bf16(gA0 + k0);
        uint4 ra1 = ld8_bf16(gA1 + k0);
        uint4 rb0 = ld8_bf16(gB0 + k0);
        uint4 rb1 = ld8_bf16(gB1 + k0);
        *(uint4*)&As[c0 * 8] = ra0;
        *(uint4*)&As[c1 * 8] = ra1;
        *(uint4*)&Bs[c0 * 8] = rb0;
        *(uint4*)&Bs[c1 * 8] = rb1;
        __syncthreads();

        short8 af[4], bfr[4];
#pragma unroll
        for (int mt = 0; mt < 4; mt++)
            af[mt] = *(const short8*)&As[(wm * 64 + mt * 16 + l16) * 32 + quad * 8];
#pragma unroll
        for (int nt = 0; nt < 4; nt++)
            bfr[nt] = *(const short8*)&Bs[(wn * 64 + nt * 16 + l16) * 32 + quad * 8];
#pragma unroll
        for (int mt = 0; mt < 4; mt++)
#pragma unroll
            for (int nt = 0; nt < 4; nt++)
                acc[mt][nt] = MFMA16(af[mt], bfr[nt], acc[mt][nt]);
        __syncthreads();
    }

    // epilogue: C/D layout row = quad*4 + reg, col = l16 (per 16x16 tile)
#pragma unroll
    for (int nt = 0; nt < 4; nt++) {
        const int n = n0 + wn * 64 + nt * 16 + l16;
        const float bv = bias[n];
#pragma unroll
        for (int mt = 0; mt < 4; mt++) {
            const int mBase = m0 + wm * 64 + mt * 16 + quad * 4;
#pragma unroll
            for (int r = 0; r < 4; r++) {
                const int m = mBase + r;
                const float v = acc[mt][nt][r] + bv;
                if (MODE == 0) {
                    // n -> (which, h, d); m -> (b, nq)
                    const int which = n >> 10, rem = n & 1023;
                    const int h = rem >> 6, d = rem & 63;
                    const int b = m >> 11, nq = m & 2047;
                    ((ushort*)out)[((((size_t)which * BATCH + b) * NHEAD + h) * SEQ + nq) * HD + d] = f2bf(v);
                } else {
                    ((float*)out)[(size_t)m * Nout + n] = v;
                }
            }
        }
    }
}

// ---------------------------------------------------------------------------
// Flash attention: grid (SEQ/64, B*H), 256 threads (4 waves x 16 q-rows).
// qkv workspace layout [3][B][H][SEQ][HD] (bf16); out wa [B][SEQ][H*HD] (bf16).
// ---------------------------------------------------------------------------
__global__ __launch_bounds__(256, 2) void attn_kernel(
    const ushort* __restrict__ qkv, ushort* __restrict__ wa)
{
    __shared__ __align__(16) ushort VT[64 * 64];        // V^T tile [d][k]
    __shared__ __align__(16) ushort Pb[4 * 16 * 64];    // per-wave P (16x64)

    const int tid  = threadIdx.x;
    const int wave = tid >> 6, lane = tid & 63;
    const int quad = lane >> 4, l16 = lane & 15;
    const int bh = blockIdx.y;
    const int b = bh >> 4, h = bh & 15;
    const size_t headOff = (size_t)bh * SEQ * HD;
    const ushort* Q  = qkv + headOff;
    const ushort* Kp = qkv + (size_t)BH * SEQ * HD + headOff;
    const ushort* Vp = qkv + (size_t)2 * BH * SEQ * HD + headOff;
    const int qbase = blockIdx.x * 64 + wave * 16;

    // Q A-fragments (rows qbase+l16, k = quad*8 + j [+32])
    short8 aq0 = *(const short8*)&Q[(size_t)(qbase + l16) * HD + quad * 8];
    short8 aq1 = *(const short8*)&Q[(size_t)(qbase + l16) * HD + 32 + quad * 8];

    f32x4 o[4];
#pragma unroll
    for (int t = 0; t < 4; t++) o[t] = (f32x4){0.f, 0.f, 0.f, 0.f};
    float mrow[4], lrow[4];
#pragma unroll
    for (int r = 0; r < 4; r++) { mrow[r] = -1e30f; lrow[r] = 0.f; }

    ushort* Pw = &Pb[wave * 16 * 64];

    for (int kt = 0; kt < SEQ / 64; kt++) {
        // stage V^T tile: thread reads 16 contiguous V elems, writes transposed
        {
            const int r = tid >> 2, cb = (tid & 3) * 16;
            const ushort* src = Vp + (size_t)(kt * 64 + r) * HD + cb;
            __align__(16) ushort tmp[16];
            *(uint4*)&tmp[0] = *(const uint4*)&src[0];
            *(uint4*)&tmp[8] = *(const uint4*)&src[8];
#pragma unroll
            for (int j = 0; j < 16; j++) VT[(cb + j) * 64 + r] = tmp[j];
        }
        __syncthreads();

        // S = Q K^T  (16 x 64 per wave), K B-frags straight from global
        f32x4 s[4];
#pragma unroll
        for (int t = 0; t < 4; t++) {
            const ushort* kr = Kp + (size_t)(kt * 64 + t * 16 + l16) * HD;
            short8 b0 = *(const short8*)&kr[quad * 8];
            short8 b1 = *(const short8*)&kr[32 + quad * 8];
            f32x4 z = (f32x4){0.f, 0.f, 0.f, 0.f};
            z = MFMA16(aq0, b0, z);
            z = MFMA16(aq1, b1, z);
            s[t] = z;
        }
#pragma unroll
        for (int t = 0; t < 4; t++)
#pragma unroll
            for (int r = 0; r < 4; r++) s[t][r] *= SCALE;

        // online softmax per row (row = quad*4 + r, cols spread over 16 lanes x 4 t)
#pragma unroll
        for (int r = 0; r < 4; r++) {
            float mx = fmaxf(fmaxf(s[0][r], s[1][r]), fmaxf(s[2][r], s[3][r]));
            mx = fmaxf(mx, __shfl_xor(mx, 1));
            mx = fmaxf(mx, __shfl_xor(mx, 2));
            mx = fmaxf(mx, __shfl_xor(mx, 4));
            mx = fmaxf(mx, __shfl_xor(mx, 8));
            const float mn = fmaxf(mrow[r], mx);
            const float alpha = __expf(mrow[r] - mn);
            mrow[r] = mn;
            float sum = 0.f;
#pragma unroll
            for (int t = 0; t < 4; t++) {
                const float pv = __expf(s[t][r] - mn);
                s[t][r] = pv;
                sum += pv;
            }
            sum += __shfl_xor(sum, 1);
            sum += __shfl_xor(sum, 2);
            sum += __shfl_xor(sum, 4);
            sum += __shfl_xor(sum, 8);
            lrow[r] = lrow[r] * alpha + sum;
#pragma unroll
            for (int t = 0; t < 4; t++) o[t][r] *= alpha;
        }

        // P: C-layout -> LDS -> A-layout (barrier fences reordering + waves)
#pragma unroll
        for (int t = 0; t < 4; t++)
#pragma unroll
            for (int r = 0; r < 4; r++)
                Pw[(quad * 4 + r) * 64 + l16 + t * 16] = f2bf(s[t][r]);
        __syncthreads();

        short8 pa0 = *(const short8*)&Pw[l16 * 64 + quad * 8];
        short8 pa1 = *(const short8*)&Pw[l16 * 64 + 32 + quad * 8];

#pragma unroll
        for (int t = 0; t < 4; t++) {
            short8 v0 = *(const short8*)&VT[(l16 + t * 16) * 64 + quad * 8];
            short8 v1 = *(const short8*)&VT[(l16 + t * 16) * 64 + 32 + quad * 8];
            o[t] = MFMA16(pa0, v0, o[t]);
            o[t] = MFMA16(pa1, v1, o[t]);
        }
        __syncthreads();   // protect VT + Pb before next iteration
    }

    // epilogue: out rows qbase+quad*4+r, cols h*64 + l16 + 16t
#pragma unroll
    for (int r = 0; r < 4; r++) {
        const float inv = 1.f / lrow[r];
        const int qrow = qbase + quad * 4 + r;
        ushort* dst = wa + ((size_t)(b * SEQ + qrow)) * DIM + h * HD;
#pragma unroll
        for (int t = 0; t < 4; t++)
            dst[l16 + t * 16] = f2bf(o[t][r] * inv);
    }
}

// ---------------------------------------------------------------------------
extern "C" void kernel_launch(void* const* d_in, const int* in_sizes, int n_in,
                              void* d_out, int out_size, void* d_ws, size_t ws_size,
                              hipStream_t stream)
{
    // Inputs fp32 (per reference); output fp32 (per reference).
    const float* x      = (const float*)d_in[0];
    const float* qkv_w  = (const float*)d_in[1];
    const float* qkv_b  = (const float*)d_in[2];
    const float* proj_w = (const float*)d_in[3];
    const float* proj_b = (const float*)d_in[4];
    float* out = (float*)d_out;

    ushort* qkv = (ushort*)d_ws;                                  // 3*B*H*SEQ*HD bf16
    ushort* wa  = qkv + (size_t)3 * BATCH * NHEAD * SEQ * HD;     // B*SEQ*DIM bf16

    const int M = BATCH * SEQ;   // 4096
    dim3 blk(256);

    // qkv = x @ qkv_w^T + qkv_b   -> scattered bf16 to [3][B][H][SEQ][HD]
    gemm_bt<0, float, ushort><<<dim3((3 * DIM) / 128, M / 128), blk, 0, stream>>>(
        x, qkv_w, qkv_b, qkv, M, 3 * DIM, DIM);

    // attention -> wa [B][SEQ][DIM] (bf16)
    attn_kernel<<<dim3(SEQ / 64, BH), blk, 0, stream>>>(qkv, wa);

    // out = wa @ proj_w^T + proj_b  (fp32 out)
    gemm_bt<1, ushort, float><<<dim3(DIM / 128, M / 128), blk, 0, stream>>>(
        wa, proj_w, proj_b, out, M, DIM, DIM);
}